// Round 1
// baseline (1339.296 us; speedup 1.0000x reference)
//
#include <hip/hip_runtime.h>

#define N_USERS 100000
#define N_ITEMS 50000
#define EMB 64
#define N_EDGES 1000000

// One wave (64 lanes) per edge; lane = embedding dim.
// Reads the opposite side's row (coalesced 256B), atomically accumulates
// into this side's new aggregate.
__global__ void gcn_scatter_kernel(const float* __restrict__ user_src,
                                   const float* __restrict__ item_src,
                                   const int* __restrict__ uidx,
                                   const int* __restrict__ iidx,
                                   float* __restrict__ user_dst,
                                   float* __restrict__ item_dst) {
    long long t = (long long)blockIdx.x * blockDim.x + threadIdx.x;
    int e = (int)(t >> 6);
    int d = (int)(t & 63);
    if (e >= N_EDGES) return;
    int u = uidx[e];
    int i = iidx[e];
    float vi = item_src[(long long)i * EMB + d];
    float vu = user_src[(long long)u * EMB + d];
    atomicAdd(&user_dst[(long long)u * EMB + d], vi);
    atomicAdd(&item_dst[(long long)i * EMB + d], vu);
}

// One wave per row: L2-normalize the aggregate in place (it is the next hop's
// gather source) and accumulate the normalized row into the output sum.
__global__ void gcn_norm_acc_kernel(float* __restrict__ agg,
                                    float* __restrict__ out,
                                    int rows) {
    long long t = (long long)blockIdx.x * blockDim.x + threadIdx.x;
    int r = (int)(t >> 6);
    int d = (int)(t & 63);
    if (r >= rows) return;
    long long off = (long long)r * EMB + d;
    float x = agg[off];
    float s = x * x;
    #pragma unroll
    for (int o = 32; o > 0; o >>= 1) s += __shfl_xor(s, o);
    float norm = sqrtf(s);
    float y = x / fmaxf(norm, 1e-12f);
    agg[off] = y;
    out[off] += y;
}

extern "C" void kernel_launch(void* const* d_in, const int* in_sizes, int n_in,
                              void* d_out, int out_size, void* d_ws, size_t ws_size,
                              hipStream_t stream) {
    const float* user_emb = (const float*)d_in[0];
    const float* item_emb = (const float*)d_in[1];
    const int*   uidx     = (const int*)d_in[2];
    const int*   iidx     = (const int*)d_in[3];

    float* out       = (float*)d_out;
    float* out_item  = out;                                // [N_ITEMS, 64]
    float* out_user  = out + (size_t)N_ITEMS * EMB;        // [N_USERS, 64]

    float* ws = (float*)d_ws;
    float* ua = ws;
    float* ub = ua + (size_t)N_USERS * EMB;
    float* ia = ub + (size_t)N_USERS * EMB;
    float* ib = ia + (size_t)N_ITEMS * EMB;

    // out = emb (then += normalized agg per hop)
    hipMemcpyAsync(out_item, item_emb, (size_t)N_ITEMS * EMB * sizeof(float),
                   hipMemcpyDeviceToDevice, stream);
    hipMemcpyAsync(out_user, user_emb, (size_t)N_USERS * EMB * sizeof(float),
                   hipMemcpyDeviceToDevice, stream);

    const float* us = user_emb;
    const float* is = item_emb;

    for (int hop = 0; hop < 3; ++hop) {
        float* ud = (hop & 1) ? ub : ua;
        float* id = (hop & 1) ? ib : ia;

        hipMemsetAsync(ud, 0, (size_t)N_USERS * EMB * sizeof(float), stream);
        hipMemsetAsync(id, 0, (size_t)N_ITEMS * EMB * sizeof(float), stream);

        long long nthreads = (long long)N_EDGES * 64;
        int blocks = (int)((nthreads + 255) / 256);
        gcn_scatter_kernel<<<blocks, 256, 0, stream>>>(us, is, uidx, iidx, ud, id);

        gcn_norm_acc_kernel<<<(N_USERS * 64) / 256, 256, 0, stream>>>(ud, out_user, N_USERS);
        gcn_norm_acc_kernel<<<(N_ITEMS * 64) / 256, 256, 0, stream>>>(id, out_item, N_ITEMS);

        us = ud;
        is = id;
    }
}

// Round 2
// 967.717 us; speedup vs baseline: 1.3840x; 1.3840x over previous
//
#include <hip/hip_runtime.h>

#define N_USERS 100000
#define N_ITEMS 50000
#define EMB 64
#define N_EDGES 1000000

// ---- CSR build ----

__global__ void hist_kernel(const int* __restrict__ uidx, const int* __restrict__ iidx,
                            int* __restrict__ cnt_u, int* __restrict__ cnt_i) {
    int e = blockIdx.x * blockDim.x + threadIdx.x;
    if (e >= N_EDGES) return;
    atomicAdd(&cnt_u[uidx[e]], 1);
    atomicAdd(&cnt_i[iidx[e]], 1);
}

// One workgroup per array (block 0: users, block 1: items). Exclusive scan of
// counts into offs[], also copies into cur[] (the fill kernel's cursors).
__global__ void scan2_kernel(const int* __restrict__ cnt_u, int* __restrict__ offs_u, int* __restrict__ cur_u,
                             const int* __restrict__ cnt_i, int* __restrict__ offs_i, int* __restrict__ cur_i) {
    const int* cnt = (blockIdx.x == 0) ? cnt_u : cnt_i;
    int* offs      = (blockIdx.x == 0) ? offs_u : offs_i;
    int* cur       = (blockIdx.x == 0) ? cur_u  : cur_i;
    int n          = (blockIdx.x == 0) ? N_USERS : N_ITEMS;

    __shared__ int wsum[16];
    __shared__ int carry;
    if (threadIdx.x == 0) carry = 0;
    __syncthreads();

    int lane = threadIdx.x & 63;
    int wid  = threadIdx.x >> 6;

    for (int base = 0; base < n; base += 1024) {
        int i = base + (int)threadIdx.x;
        int c = carry;                       // read before any write this iter
        int v = (i < n) ? cnt[i] : 0;
        int x = v;                           // inclusive wave scan
        #pragma unroll
        for (int o = 1; o < 64; o <<= 1) {
            int t = __shfl_up(x, o);
            if (lane >= o) x += t;
        }
        if (lane == 63) wsum[wid] = x;
        __syncthreads();                     // S1: wsum visible
        int woff = 0;
        for (int w = 0; w < wid; ++w) woff += wsum[w];
        if (i < n) {
            int excl = c + woff + x - v;
            offs[i] = excl;
            cur[i]  = excl;
        }
        __syncthreads();                     // S2: all reads of carry/wsum done
        if (threadIdx.x == 1023) carry = c + woff + x;  // chunk total
        __syncthreads();                     // S3: carry visible for next iter
    }
    if (threadIdx.x == 0) offs[n] = carry;
}

// Scatter each edge's OPPOSITE index into its destination's CSR slot.
__global__ void fill_kernel(const int* __restrict__ uidx, const int* __restrict__ iidx,
                            int* __restrict__ cur_u, int* __restrict__ cur_i,
                            int* __restrict__ list_u, int* __restrict__ list_i) {
    int e = blockIdx.x * blockDim.x + threadIdx.x;
    if (e >= N_EDGES) return;
    int u = uidx[e];
    int i = iidx[e];
    int pu = atomicAdd(&cur_u[u], 1);
    list_u[pu] = i;                 // user u gathers from item i
    int pi = atomicAdd(&cur_i[i], 1);
    list_i[pi] = u;                 // item i gathers from user u
}

// ---- Per-hop fused gather + segment-sum + L2-normalize + output accumulate ----
// One 64-lane wave per destination row (lane = dim). Row reads are 256B coalesced.
__global__ void gather_norm_kernel(const float* __restrict__ src,   // opposite side, prev hop
                                   const int* __restrict__ offs,
                                   const int* __restrict__ list,
                                   float* __restrict__ agg,         // normalized agg (next hop src)
                                   float* __restrict__ out,         // += normalized
                                   int rows) {
    int t = blockIdx.x * blockDim.x + threadIdx.x;
    int r = t >> 6;
    int d = t & 63;
    if (r >= rows) return;
    int beg = offs[r];
    int end = offs[r + 1];
    float s = 0.f;
    for (int k = beg; k < end; ++k) {
        int j = list[k];                       // wave-uniform
        s += src[(size_t)j * EMB + d];
    }
    float q = s * s;
    #pragma unroll
    for (int o = 32; o > 0; o >>= 1) q += __shfl_xor(q, o);
    float y = s / fmaxf(sqrtf(q), 1e-12f);
    size_t off = (size_t)r * EMB + d;
    agg[off] = y;
    out[off] += y;
}

extern "C" void kernel_launch(void* const* d_in, const int* in_sizes, int n_in,
                              void* d_out, int out_size, void* d_ws, size_t ws_size,
                              hipStream_t stream) {
    const float* user_emb = (const float*)d_in[0];
    const float* item_emb = (const float*)d_in[1];
    const int*   uidx     = (const int*)d_in[2];
    const int*   iidx     = (const int*)d_in[3];

    float* out      = (float*)d_out;
    float* out_item = out;                           // [N_ITEMS, 64]
    float* out_user = out + (size_t)N_ITEMS * EMB;   // [N_USERS, 64]

    // workspace layout
    float* ws = (float*)d_ws;
    float* ua = ws;
    float* ub = ua + (size_t)N_USERS * EMB;
    float* ia = ub + (size_t)N_USERS * EMB;
    float* ib = ia + (size_t)N_ITEMS * EMB;
    int* cnt_u  = (int*)(ib + (size_t)N_ITEMS * EMB);
    int* cnt_i  = cnt_u + N_USERS;
    int* offs_u = cnt_i + N_ITEMS;
    int* offs_i = offs_u + (N_USERS + 1);
    int* cur_u  = offs_i + (N_ITEMS + 1);
    int* cur_i  = cur_u + N_USERS;
    int* list_u = cur_i + N_ITEMS;
    int* list_i = list_u + N_EDGES;

    // --- build CSR (indices are fixed per call; reused across 3 hops) ---
    hipMemsetAsync(cnt_u, 0, (size_t)(N_USERS + N_ITEMS) * sizeof(int), stream);
    hist_kernel<<<(N_EDGES + 255) / 256, 256, 0, stream>>>(uidx, iidx, cnt_u, cnt_i);
    scan2_kernel<<<2, 1024, 0, stream>>>(cnt_u, offs_u, cur_u, cnt_i, offs_i, cur_i);
    fill_kernel<<<(N_EDGES + 255) / 256, 256, 0, stream>>>(uidx, iidx, cur_u, cur_i, list_u, list_i);

    // out = emb (then += normalized agg per hop)
    hipMemcpyAsync(out_item, item_emb, (size_t)N_ITEMS * EMB * sizeof(float),
                   hipMemcpyDeviceToDevice, stream);
    hipMemcpyAsync(out_user, user_emb, (size_t)N_USERS * EMB * sizeof(float),
                   hipMemcpyDeviceToDevice, stream);

    const float* us = user_emb;
    const float* is = item_emb;

    for (int hop = 0; hop < 3; ++hop) {
        float* ud = (hop & 1) ? ub : ua;
        float* id = (hop & 1) ? ib : ia;

        gather_norm_kernel<<<(N_USERS * EMB) / 256, 256, 0, stream>>>(
            is, offs_u, list_u, ud, out_user, N_USERS);
        gather_norm_kernel<<<(N_ITEMS * EMB) / 256, 256, 0, stream>>>(
            us, offs_i, list_i, id, out_item, N_ITEMS);

        us = ud;
        is = id;
    }
}

// Round 3
// 517.288 us; speedup vs baseline: 2.5891x; 1.8708x over previous
//
#include <hip/hip_runtime.h>

#define N_USERS 100000
#define N_ITEMS 50000
#define EMB 64
#define N_EDGES 1000000

#define TILE 4096
#define NT_U 25   // ceil(N_USERS/TILE)
#define NT_I 13   // ceil(N_ITEMS/TILE)
#define NT_TOT (NT_U + NT_I)

// ---- CSR build ----

__global__ void hist_kernel(const int* __restrict__ uidx, const int* __restrict__ iidx,
                            int* __restrict__ cnt_u, int* __restrict__ cnt_i) {
    int e = blockIdx.x * blockDim.x + threadIdx.x;
    if (e >= N_EDGES) return;
    atomicAdd(&cnt_u[uidx[e]], 1);
    atomicAdd(&cnt_i[iidx[e]], 1);
}

// Per-tile sums of the count arrays (user tiles 0..NT_U-1, item tiles NT_U..).
__global__ void tile_sum_kernel(const int* __restrict__ cnt_u, const int* __restrict__ cnt_i,
                                int* __restrict__ partial) {
    int blk = blockIdx.x;
    int seg = (blk < NT_U) ? 0 : 1;
    const int* cnt = seg ? cnt_i : cnt_u;
    int n = seg ? N_ITEMS : N_USERS;
    int tile = seg ? blk - NT_U : blk;
    int base = tile * TILE;
    int tid = threadIdx.x;
    int s = 0;
    for (int i = tid; i < TILE; i += 256) {
        int idx = base + i;
        if (idx < n) s += cnt[idx];
    }
    #pragma unroll
    for (int o = 32; o > 0; o >>= 1) s += __shfl_xor(s, o);
    __shared__ int wsum[4];
    if ((tid & 63) == 0) wsum[tid >> 6] = s;
    __syncthreads();
    if (tid == 0) partial[blk] = wsum[0] + wsum[1] + wsum[2] + wsum[3];
}

// Exclusive scan within each tile + tile base from partial[]; writes offs & cur.
__global__ void scan_write_kernel(const int* __restrict__ cnt_u, const int* __restrict__ cnt_i,
                                  const int* __restrict__ partial,
                                  int* __restrict__ offs_u, int* __restrict__ cur_u,
                                  int* __restrict__ offs_i, int* __restrict__ cur_i) {
    int blk = blockIdx.x;
    int seg = (blk < NT_U) ? 0 : 1;
    const int* cnt = seg ? cnt_i : cnt_u;
    int* offs = seg ? offs_i : offs_u;
    int* cur  = seg ? cur_i  : cur_u;
    int n = seg ? N_ITEMS : N_USERS;
    int tfirst = seg ? NT_U : 0;
    int ntiles = seg ? NT_I : NT_U;
    int tile = blk - tfirst;
    int base = tile * TILE;
    int tid = threadIdx.x;

    __shared__ int lds[TILE];
    for (int i = tid; i < TILE; i += 256) {
        int idx = base + i;
        lds[i] = (idx < n) ? cnt[idx] : 0;
    }
    __syncthreads();

    int pbase = 0;
    for (int t = 0; t < tile; ++t) pbase += partial[tfirst + t];

    int tsum = 0;
    #pragma unroll
    for (int i = 0; i < 16; ++i) tsum += lds[tid * 16 + i];

    int lane = tid & 63, wid = tid >> 6;
    int x = tsum;
    #pragma unroll
    for (int o = 1; o < 64; o <<= 1) {
        int t = __shfl_up(x, o);
        if (lane >= o) x += t;
    }
    __shared__ int wsum[4];
    if (lane == 63) wsum[wid] = x;
    __syncthreads();
    int wbase = 0;
    for (int w = 0; w < wid; ++w) wbase += wsum[w];

    int run = pbase + wbase + x - tsum;   // exclusive base for this thread
    #pragma unroll
    for (int i = 0; i < 16; ++i) {
        int idx = base + tid * 16 + i;
        if (idx < n) { offs[idx] = run; cur[idx] = run; }
        run += lds[tid * 16 + i];
    }
    if (tile == ntiles - 1 && tid == 255) offs[n] = run;  // segment total
}

// Scatter each edge's OPPOSITE index into its destination's CSR slot.
__global__ void fill_kernel(const int* __restrict__ uidx, const int* __restrict__ iidx,
                            int* __restrict__ cur_u, int* __restrict__ cur_i,
                            int* __restrict__ list_u, int* __restrict__ list_i) {
    int e = blockIdx.x * blockDim.x + threadIdx.x;
    if (e >= N_EDGES) return;
    int u = uidx[e];
    int i = iidx[e];
    int pu = atomicAdd(&cur_u[u], 1);
    list_u[pu] = i;
    int pi = atomicAdd(&cur_i[i], 1);
    list_i[pi] = u;
}

// ---- Fused per-hop: gather + segment-sum + L2-normalize + output accumulate,
// both sides in one launch. One 64-lane wave per destination row.
__global__ void gather_norm_both(const float* __restrict__ srcU,  // users gather from item table
                                 const float* __restrict__ srcI,  // items gather from user table
                                 const int* __restrict__ offs_u, const int* __restrict__ list_u,
                                 const int* __restrict__ offs_i, const int* __restrict__ list_i,
                                 float* __restrict__ aggU, float* __restrict__ aggI,
                                 float* __restrict__ outU, float* __restrict__ outI,
                                 const float* __restrict__ initU, const float* __restrict__ initI,
                                 int first) {
    int t = blockIdx.x * blockDim.x + threadIdx.x;
    int r = t >> 6;
    int d = t & 63;
    const float* src; const int* offs; const int* list;
    float* agg; float* out; const float* init;
    int rr;
    if (r < N_USERS) {
        src = srcU; offs = offs_u; list = list_u;
        agg = aggU; out = outU; init = initU; rr = r;
    } else {
        src = srcI; offs = offs_i; list = list_i;
        agg = aggI; out = outI; init = initI; rr = r - N_USERS;
    }
    int beg = offs[rr];
    int end = offs[rr + 1];
    int g = end - beg;
    int gc = (g < 64) ? g : 64;

    // stage up to 64 neighbor indices, one per lane
    int jl = (d < gc) ? list[beg + d] : 0;

    float s0 = 0.f, s1 = 0.f, s2 = 0.f, s3 = 0.f;
    int k = 0;
    for (; k + 4 <= gc; k += 4) {
        int j0 = __shfl(jl, k);
        int j1 = __shfl(jl, k + 1);
        int j2 = __shfl(jl, k + 2);
        int j3 = __shfl(jl, k + 3);
        s0 += src[(size_t)j0 * EMB + d];
        s1 += src[(size_t)j1 * EMB + d];
        s2 += src[(size_t)j2 * EMB + d];
        s3 += src[(size_t)j3 * EMB + d];
    }
    for (; k < gc; ++k) s0 += src[(size_t)__shfl(jl, k) * EMB + d];
    for (int kk = beg + 64; kk < end; ++kk) s0 += src[(size_t)list[kk] * EMB + d];

    float s = (s0 + s1) + (s2 + s3);
    float q = s * s;
    #pragma unroll
    for (int o = 32; o > 0; o >>= 1) q += __shfl_xor(q, o);
    float y = s / fmaxf(sqrtf(q), 1e-12f);

    size_t off = (size_t)rr * EMB + d;
    agg[off] = y;
    out[off] = first ? (init[off] + y) : (out[off] + y);
}

extern "C" void kernel_launch(void* const* d_in, const int* in_sizes, int n_in,
                              void* d_out, int out_size, void* d_ws, size_t ws_size,
                              hipStream_t stream) {
    const float* user_emb = (const float*)d_in[0];
    const float* item_emb = (const float*)d_in[1];
    const int*   uidx     = (const int*)d_in[2];
    const int*   iidx     = (const int*)d_in[3];

    float* out      = (float*)d_out;
    float* out_item = out;                           // [N_ITEMS, 64]
    float* out_user = out + (size_t)N_ITEMS * EMB;   // [N_USERS, 64]

    float* ws = (float*)d_ws;
    float* ua = ws;
    float* ub = ua + (size_t)N_USERS * EMB;
    float* ia = ub + (size_t)N_USERS * EMB;
    float* ib = ia + (size_t)N_ITEMS * EMB;
    int* cnt_u   = (int*)(ib + (size_t)N_ITEMS * EMB);
    int* cnt_i   = cnt_u + N_USERS;
    int* offs_u  = cnt_i + N_ITEMS;
    int* offs_i  = offs_u + (N_USERS + 1);
    int* cur_u   = offs_i + (N_ITEMS + 1);
    int* cur_i   = cur_u + N_USERS;
    int* partial = cur_i + N_ITEMS;
    int* list_u  = partial + NT_TOT;
    int* list_i  = list_u + N_EDGES;

    // --- build CSR ---
    hipMemsetAsync(cnt_u, 0, (size_t)(N_USERS + N_ITEMS) * sizeof(int), stream);
    hist_kernel<<<(N_EDGES + 255) / 256, 256, 0, stream>>>(uidx, iidx, cnt_u, cnt_i);
    tile_sum_kernel<<<NT_TOT, 256, 0, stream>>>(cnt_u, cnt_i, partial);
    scan_write_kernel<<<NT_TOT, 256, 0, stream>>>(cnt_u, cnt_i, partial,
                                                  offs_u, cur_u, offs_i, cur_i);
    fill_kernel<<<(N_EDGES + 255) / 256, 256, 0, stream>>>(uidx, iidx, cur_u, cur_i,
                                                           list_u, list_i);

    // --- 3 hops, both sides fused per launch ---
    const float* us = user_emb;
    const float* is = item_emb;
    const int nblocks = ((N_USERS + N_ITEMS) * EMB) / 256;  // 37500

    for (int hop = 0; hop < 3; ++hop) {
        float* ud = (hop & 1) ? ub : ua;
        float* id = (hop & 1) ? ib : ia;

        gather_norm_both<<<nblocks, 256, 0, stream>>>(
            is, us, offs_u, list_u, offs_i, list_i,
            ud, id, out_user, out_item, user_emb, item_emb, hop == 0);

        us = ud;
        is = id;
    }
}

// Round 4
// 462.372 us; speedup vs baseline: 2.8966x; 1.1188x over previous
//
#include <hip/hip_runtime.h>

#define N_USERS 100000
#define N_ITEMS 50000
#define EMB 64
#define N_EDGES 1000000

#define TILE 4096
#define NT_U 25   // ceil(N_USERS/TILE)
#define NT_I 13   // ceil(N_ITEMS/TILE)
#define NT_TOT (NT_U + NT_I)

typedef unsigned short u16;
typedef u16 us8 __attribute__((ext_vector_type(8)));
typedef u16 us4 __attribute__((ext_vector_type(4)));
typedef float f4 __attribute__((ext_vector_type(4)));

static __device__ __forceinline__ float bf2f(u16 h) {
    return __uint_as_float(((unsigned)h) << 16);
}
static __device__ __forceinline__ u16 f2bf(float f) {
    unsigned u = __float_as_uint(f);
    return (u16)((u + 0x7FFFu + ((u >> 16) & 1u)) >> 16);
}

// f32 -> bf16 table conversion, 4 elems/thread
__global__ void conv_kernel(const float* __restrict__ a, u16* __restrict__ b, int n4) {
    int t = blockIdx.x * blockDim.x + threadIdx.x;
    if (t >= n4) return;
    f4 v = ((const f4*)a)[t];
    us4 w;
    w.x = f2bf(v.x); w.y = f2bf(v.y); w.z = f2bf(v.z); w.w = f2bf(v.w);
    ((us4*)b)[t] = w;
}

// ---- CSR build ----

__global__ void hist_kernel(const int* __restrict__ uidx, const int* __restrict__ iidx,
                            int* __restrict__ cnt_u, int* __restrict__ cnt_i) {
    int e = blockIdx.x * blockDim.x + threadIdx.x;
    if (e >= N_EDGES) return;
    atomicAdd(&cnt_u[uidx[e]], 1);
    atomicAdd(&cnt_i[iidx[e]], 1);
}

__global__ void tile_sum_kernel(const int* __restrict__ cnt_u, const int* __restrict__ cnt_i,
                                int* __restrict__ partial) {
    int blk = blockIdx.x;
    int seg = (blk < NT_U) ? 0 : 1;
    const int* cnt = seg ? cnt_i : cnt_u;
    int n = seg ? N_ITEMS : N_USERS;
    int tile = seg ? blk - NT_U : blk;
    int base = tile * TILE;
    int tid = threadIdx.x;
    int s = 0;
    for (int i = tid; i < TILE; i += 256) {
        int idx = base + i;
        if (idx < n) s += cnt[idx];
    }
    #pragma unroll
    for (int o = 32; o > 0; o >>= 1) s += __shfl_xor(s, o);
    __shared__ int wsum[4];
    if ((tid & 63) == 0) wsum[tid >> 6] = s;
    __syncthreads();
    if (tid == 0) partial[blk] = wsum[0] + wsum[1] + wsum[2] + wsum[3];
}

__global__ void scan_write_kernel(const int* __restrict__ cnt_u, const int* __restrict__ cnt_i,
                                  const int* __restrict__ partial,
                                  int* __restrict__ offs_u, int* __restrict__ cur_u,
                                  int* __restrict__ offs_i, int* __restrict__ cur_i) {
    int blk = blockIdx.x;
    int seg = (blk < NT_U) ? 0 : 1;
    const int* cnt = seg ? cnt_i : cnt_u;
    int* offs = seg ? offs_i : offs_u;
    int* cur  = seg ? cur_i  : cur_u;
    int n = seg ? N_ITEMS : N_USERS;
    int tfirst = seg ? NT_U : 0;
    int ntiles = seg ? NT_I : NT_U;
    int tile = blk - tfirst;
    int base = tile * TILE;
    int tid = threadIdx.x;

    __shared__ int lds[TILE];
    for (int i = tid; i < TILE; i += 256) {
        int idx = base + i;
        lds[i] = (idx < n) ? cnt[idx] : 0;
    }
    __syncthreads();

    int pbase = 0;
    for (int t = 0; t < tile; ++t) pbase += partial[tfirst + t];

    int tsum = 0;
    #pragma unroll
    for (int i = 0; i < 16; ++i) tsum += lds[tid * 16 + i];

    int lane = tid & 63, wid = tid >> 6;
    int x = tsum;
    #pragma unroll
    for (int o = 1; o < 64; o <<= 1) {
        int t = __shfl_up(x, o);
        if (lane >= o) x += t;
    }
    __shared__ int wsum[4];
    if (lane == 63) wsum[wid] = x;
    __syncthreads();
    int wbase = 0;
    for (int w = 0; w < wid; ++w) wbase += wsum[w];

    int run = pbase + wbase + x - tsum;
    #pragma unroll
    for (int i = 0; i < 16; ++i) {
        int idx = base + tid * 16 + i;
        if (idx < n) { offs[idx] = run; cur[idx] = run; }
        run += lds[tid * 16 + i];
    }
    if (tile == ntiles - 1 && tid == 255) offs[n] = run;
}

__global__ void fill_kernel(const int* __restrict__ uidx, const int* __restrict__ iidx,
                            int* __restrict__ cur_u, int* __restrict__ cur_i,
                            int* __restrict__ list_u, int* __restrict__ list_i) {
    int e = blockIdx.x * blockDim.x + threadIdx.x;
    if (e >= N_EDGES) return;
    int u = uidx[e];
    int i = iidx[e];
    int pu = atomicAdd(&cur_u[u], 1);
    list_u[pu] = i;
    int pi = atomicAdd(&cur_i[i], 1);
    list_i[pi] = u;
}

// ---- Fused per-hop gather + segment-sum + L2-norm + out accumulate ----
// One wave per destination row. bf16 rows = 128B = 8 lanes x 16B, so one wave
// load instruction fetches 8 edges' rows. grp = lane>>3 picks the edge,
// sub = lane&7 picks the 8-dim chunk.
__global__ void gather_norm_v(const u16* __restrict__ srcU,  // item table (users gather)
                              const u16* __restrict__ srcI,  // user table (items gather)
                              const int* __restrict__ offs_u, const int* __restrict__ list_u,
                              const int* __restrict__ offs_i, const int* __restrict__ list_i,
                              u16* __restrict__ aggU, u16* __restrict__ aggI,
                              float* __restrict__ outU, float* __restrict__ outI,
                              const float* __restrict__ initU, const float* __restrict__ initI,
                              int first) {
    int t = blockIdx.x * blockDim.x + threadIdx.x;
    int r = t >> 6;
    int d = t & 63;
    const u16* src; const int* offs; const int* list;
    u16* agg; float* out; const float* init; int rr;
    if (r < N_USERS) {
        src = srcU; offs = offs_u; list = list_u;
        agg = aggU; out = outU; init = initU; rr = r;
    } else {
        src = srcI; offs = offs_i; list = list_i;
        agg = aggI; out = outI; init = initI; rr = r - N_USERS;
    }
    int beg = offs[rr];
    int end = offs[rr + 1];
    int g = end - beg;
    int gc = (g < 64) ? g : 64;
    int grp = d >> 3, sub = d & 7;

    int jl = (d < gc) ? list[beg + d] : 0;

    float acc[8] = {0.f, 0.f, 0.f, 0.f, 0.f, 0.f, 0.f, 0.f};

    int k = 0;
    for (; k + 8 <= gc; k += 8) {
        int j = __shfl(jl, k + grp);
        us8 v = *(const us8*)(src + (size_t)j * EMB + sub * 8);
        #pragma unroll
        for (int i = 0; i < 8; ++i) acc[i] += bf2f(v[i]);
    }
    int m = gc - k;
    if (m > 0) {
        int sl = k + ((grp < m) ? grp : 0);
        int j = __shfl(jl, sl);           // all lanes execute the shfl
        if (grp < m) {
            us8 v = *(const us8*)(src + (size_t)j * EMB + sub * 8);
            #pragma unroll
            for (int i = 0; i < 8; ++i) acc[i] += bf2f(v[i]);
        }
    }
    // degree > 64 overflow (essentially never at these degree distributions)
    for (int kk = beg + 64 + grp; kk < end; kk += 8) {
        int j = list[kk];
        us8 v = *(const us8*)(src + (size_t)j * EMB + sub * 8);
        #pragma unroll
        for (int i = 0; i < 8; ++i) acc[i] += bf2f(v[i]);
    }

    // fold the 8 edge-groups: lanes {sub, sub+8, ..., sub+56} hold partials
    #pragma unroll
    for (int o = 8; o < 64; o <<= 1) {
        #pragma unroll
        for (int i = 0; i < 8; ++i) acc[i] += __shfl_xor(acc[i], o);
    }

    float q = 0.f;
    #pragma unroll
    for (int i = 0; i < 8; ++i) q += acc[i] * acc[i];
    q += __shfl_xor(q, 1);
    q += __shfl_xor(q, 2);
    q += __shfl_xor(q, 4);

    float inv = 1.f / fmaxf(sqrtf(q), 1e-12f);
    float y[8];
    #pragma unroll
    for (int i = 0; i < 8; ++i) y[i] = acc[i] * inv;

    if (grp == 0) {
        size_t ro = (size_t)rr * EMB + sub * 8;
        us8 w;
        #pragma unroll
        for (int i = 0; i < 8; ++i) w[i] = f2bf(y[i]);
        *(us8*)(agg + ro) = w;

        f4 a0 = {y[0], y[1], y[2], y[3]};
        f4 a1 = {y[4], y[5], y[6], y[7]};
        f4 b0, b1;
        if (first) {
            b0 = *(const f4*)(init + ro);
            b1 = *(const f4*)(init + ro + 4);
        } else {
            b0 = *(const f4*)(out + ro);
            b1 = *(const f4*)(out + ro + 4);
        }
        *(f4*)(out + ro)     = a0 + b0;
        *(f4*)(out + ro + 4) = a1 + b1;
    }
}

extern "C" void kernel_launch(void* const* d_in, const int* in_sizes, int n_in,
                              void* d_out, int out_size, void* d_ws, size_t ws_size,
                              hipStream_t stream) {
    const float* user_emb = (const float*)d_in[0];
    const float* item_emb = (const float*)d_in[1];
    const int*   uidx     = (const int*)d_in[2];
    const int*   iidx     = (const int*)d_in[3];

    float* out      = (float*)d_out;
    float* out_item = out;                           // [N_ITEMS, 64]
    float* out_user = out + (size_t)N_ITEMS * EMB;   // [N_USERS, 64]

    // workspace layout (bf16 tables first, 16B-aligned)
    u16* ws16    = (u16*)d_ws;
    u16* ua_bf   = ws16;
    u16* ub_bf   = ua_bf + (size_t)N_USERS * EMB;
    u16* ia_bf   = ub_bf + (size_t)N_USERS * EMB;
    u16* ib_bf   = ia_bf + (size_t)N_ITEMS * EMB;
    u16* uemb_bf = ib_bf + (size_t)N_ITEMS * EMB;
    u16* iemb_bf = uemb_bf + (size_t)N_USERS * EMB;
    int* cnt_u   = (int*)(iemb_bf + (size_t)N_ITEMS * EMB);
    int* cnt_i   = cnt_u + N_USERS;
    int* offs_u  = cnt_i + N_ITEMS;
    int* offs_i  = offs_u + (N_USERS + 1);
    int* cur_u   = offs_i + (N_ITEMS + 1);
    int* cur_i   = cur_u + N_USERS;
    int* partial = cur_i + N_ITEMS;
    int* list_u  = partial + NT_TOT + 1;   // +1 keeps 8B alignment headroom
    int* list_i  = list_u + N_EDGES;

    // --- bf16 copies of the embeddings (hop-0 gather sources) ---
    conv_kernel<<<(N_USERS * EMB / 4 + 255) / 256, 256, 0, stream>>>(user_emb, uemb_bf, N_USERS * EMB / 4);
    conv_kernel<<<(N_ITEMS * EMB / 4 + 255) / 256, 256, 0, stream>>>(item_emb, iemb_bf, N_ITEMS * EMB / 4);

    // --- build CSR ---
    hipMemsetAsync(cnt_u, 0, (size_t)(N_USERS + N_ITEMS) * sizeof(int), stream);
    hist_kernel<<<(N_EDGES + 255) / 256, 256, 0, stream>>>(uidx, iidx, cnt_u, cnt_i);
    tile_sum_kernel<<<NT_TOT, 256, 0, stream>>>(cnt_u, cnt_i, partial);
    scan_write_kernel<<<NT_TOT, 256, 0, stream>>>(cnt_u, cnt_i, partial,
                                                  offs_u, cur_u, offs_i, cur_i);
    fill_kernel<<<(N_EDGES + 255) / 256, 256, 0, stream>>>(uidx, iidx, cur_u, cur_i,
                                                           list_u, list_i);

    // --- 3 hops ---
    const u16* us_bf = uemb_bf;
    const u16* is_bf = iemb_bf;
    const int nblocks = ((N_USERS + N_ITEMS) * EMB) / 256;  // 37500

    for (int hop = 0; hop < 3; ++hop) {
        u16* ud = (hop & 1) ? ub_bf : ua_bf;
        u16* id = (hop & 1) ? ib_bf : ia_bf;

        gather_norm_v<<<nblocks, 256, 0, stream>>>(
            is_bf, us_bf, offs_u, list_u, offs_i, list_i,
            ud, id, out_user, out_item, user_emb, item_emb, hop == 0);

        us_bf = ud;
        is_bf = id;
    }
}

// Round 5
// 257.474 us; speedup vs baseline: 5.2017x; 1.7958x over previous
//
#include <hip/hip_runtime.h>

#define N_USERS 100000
#define N_ITEMS 50000
#define EMB 64
#define N_EDGES 1000000

// ---- bucketed CSR build parameters ----
#define SH_U 9                 // 512 users per bucket
#define SH_I 8                 // 256 items per bucket
#define NBUK 196               // ceil(100000/512) == ceil(50000/256) == 196
#define B1 256                 // pass-A blocks
#define CHUNK ((N_EDGES + B1 - 1) / B1)   // 3907
#define HN (2 * NBUK * B1)     // 100352 histogram entries (logical, bucket-major)
#define HTILE 4096
#define HTILES ((HN + HTILE - 1) / HTILE) // 25

typedef unsigned short u16;
typedef u16 us8 __attribute__((ext_vector_type(8)));
typedef u16 us4 __attribute__((ext_vector_type(4)));
typedef float f4 __attribute__((ext_vector_type(4)));

static __device__ __forceinline__ float bf2f(u16 h) {
    return __uint_as_float(((unsigned)h) << 16);
}
static __device__ __forceinline__ u16 f2bf(float f) {
    unsigned u = __float_as_uint(f);
    return (u16)((u + 0x7FFFu + ((u >> 16) & 1u)) >> 16);
}

// logical hist index L (= (side*NBUK + b)*B1 + blk) -> physical (block-major, coalesced writes)
static __device__ __forceinline__ int hphys(int L) {
    int sb = L >> 8;          // B1 == 256
    int blk = L & 255;
    return blk * (2 * NBUK) + sb;
}

// f32 -> bf16 table conversion, 4 elems/thread
__global__ void conv_kernel(const float* __restrict__ a, u16* __restrict__ b, int n4) {
    int t = blockIdx.x * blockDim.x + threadIdx.x;
    if (t >= n4) return;
    f4 v = ((const f4*)a)[t];
    us4 w;
    w.x = f2bf(v.x); w.y = f2bf(v.y); w.z = f2bf(v.z); w.w = f2bf(v.w);
    ((us4*)b)[t] = w;
}

// ---- Pass A1: per-block bucket histograms ----
__global__ void histA_kernel(const int* __restrict__ uidx, const int* __restrict__ iidx,
                             int* __restrict__ H) {
    __shared__ int hu[NBUK];
    __shared__ int hi[NBUK];
    int tid = threadIdx.x, blk = blockIdx.x;
    for (int b = tid; b < NBUK; b += 256) { hu[b] = 0; hi[b] = 0; }
    __syncthreads();
    int e0 = blk * CHUNK;
    int e1 = e0 + CHUNK; if (e1 > N_EDGES) e1 = N_EDGES;
    for (int e = e0 + tid; e < e1; e += 256) {
        atomicAdd(&hu[uidx[e] >> SH_U], 1);
        atomicAdd(&hi[iidx[e] >> SH_I], 1);
    }
    __syncthreads();
    int* Hb = H + blk * (2 * NBUK);       // physical: block-major, coalesced
    for (int b = tid; b < NBUK; b += 256) {
        Hb[b] = hu[b];
        Hb[NBUK + b] = hi[b];
    }
}

// ---- Pass A2: 2-level exclusive scan over logical order ----
__global__ void hscan_tile_kernel(const int* __restrict__ H, int* __restrict__ part) {
    int t = blockIdx.x, tid = threadIdx.x;
    int base = t * HTILE;
    int s = 0;
    for (int i = tid; i < HTILE; i += 256) {
        int L = base + i;
        if (L < HN) s += H[hphys(L)];
    }
    #pragma unroll
    for (int o = 32; o > 0; o >>= 1) s += __shfl_xor(s, o);
    __shared__ int wsum[4];
    if ((tid & 63) == 0) wsum[tid >> 6] = s;
    __syncthreads();
    if (tid == 0) part[t] = wsum[0] + wsum[1] + wsum[2] + wsum[3];
}

__global__ void hscan_write_kernel(const int* __restrict__ H, const int* __restrict__ part,
                                   int* __restrict__ HB) {
    int t = blockIdx.x, tid = threadIdx.x;
    int base = t * HTILE;

    __shared__ int lds[HTILE];
    for (int i = tid; i < HTILE; i += 256) {
        int L = base + i;
        lds[i] = (L < HN) ? H[hphys(L)] : 0;
    }
    __syncthreads();

    int pbase = 0;
    for (int p = 0; p < t; ++p) pbase += part[p];

    int tsum = 0;
    #pragma unroll
    for (int i = 0; i < 16; ++i) tsum += lds[tid * 16 + i];

    int lane = tid & 63, wid = tid >> 6;
    int x = tsum;
    #pragma unroll
    for (int o = 1; o < 64; o <<= 1) {
        int tt = __shfl_up(x, o);
        if (lane >= o) x += tt;
    }
    __shared__ int wsum[4];
    if (lane == 63) wsum[wid] = x;
    __syncthreads();
    int wbase = 0;
    for (int w = 0; w < wid; ++w) wbase += wsum[w];

    int run = pbase + wbase + x - tsum;
    #pragma unroll
    for (int i = 0; i < 16; ++i) {
        int L = base + tid * 16 + i;
        if (L < HN) HB[L] = run;
        run += lds[tid * 16 + i];
    }
}

// ---- Pass A3: scatter edges into bucket-segmented record array ----
// user record: (u&511)<<16 | item   (9+16 bits); item record: (i&255)<<17 | user (8+17 bits)
__global__ void scatterA_kernel(const int* __restrict__ uidx, const int* __restrict__ iidx,
                                const int* __restrict__ HB, int* __restrict__ rec) {
    __shared__ int cu[NBUK];
    __shared__ int ci[NBUK];
    int tid = threadIdx.x, blk = blockIdx.x;
    for (int sb = tid; sb < 2 * NBUK; sb += 256) {
        int v = HB[sb * B1 + blk];
        if (sb < NBUK) cu[sb] = v; else ci[sb - NBUK] = v;
    }
    __syncthreads();
    int e0 = blk * CHUNK;
    int e1 = e0 + CHUNK; if (e1 > N_EDGES) e1 = N_EDGES;
    for (int e = e0 + tid; e < e1; e += 256) {
        int u = uidx[e];
        int i = iidx[e];
        int pu = atomicAdd(&cu[u >> SH_U], 1);
        rec[pu] = ((u & 511) << 16) | i;
        int pi = atomicAdd(&ci[i >> SH_I], 1);
        rec[pi] = ((i & 255) << 17) | u;
    }
}

// ---- Pass B: per-bucket CSR finalize (offs + list), writes localized ----
__global__ void bucketB_kernel(const int* __restrict__ HB, const int* __restrict__ rec,
                               int* __restrict__ offs_u, int* __restrict__ offs_i,
                               int* __restrict__ list) {
    int sb = blockIdx.x, tid = threadIdx.x;
    int side = (sb >= NBUK) ? 1 : 0;
    int b = sb - side * NBUK;
    int start = HB[sb * B1];
    int end = (sb == 2 * NBUK - 1) ? 2 * N_EDGES : HB[(sb + 1) * B1];
    int shift = side ? 17 : 16;
    int mask  = side ? 0x1FFFF : 0xFFFF;
    int nd    = side ? 256 : 512;
    int dbase = side ? (b << SH_I) : (b << SH_U);
    int n     = side ? N_ITEMS : N_USERS;
    int rel   = start - side * N_EDGES;
    int* offs = side ? offs_i : offs_u;

    __shared__ int cnt[512];
    __shared__ int scn[512];
    __shared__ int wsum[4];
    if (tid < 256) { cnt[tid] = 0; cnt[256 + tid] = 0; }
    __syncthreads();

    for (int r = start + tid; r < end; r += 256)
        atomicAdd(&cnt[rec[r] >> shift], 1);
    __syncthreads();

    // block exclusive scan of 512 (256 threads x 2)
    int a0 = cnt[2 * tid], a1 = cnt[2 * tid + 1];
    int s = a0 + a1;
    int lane = tid & 63, wid = tid >> 6;
    int x = s;
    #pragma unroll
    for (int o = 1; o < 64; o <<= 1) {
        int tt = __shfl_up(x, o);
        if (lane >= o) x += tt;
    }
    if (lane == 63) wsum[wid] = x;
    __syncthreads();
    int wbase = 0;
    for (int w = 0; w < wid; ++w) wbase += wsum[w];
    int excl = wbase + x - s;
    scn[2 * tid] = excl;
    scn[2 * tid + 1] = excl + a0;
    __syncthreads();

    // offs for this bucket's dests
    for (int dl = tid; dl < nd; dl += 256) {
        int dg = dbase + dl;
        if (dg < n) offs[dg] = rel + scn[dl];
    }
    if (b == NBUK - 1 && tid == 0) offs[n] = (end - side * N_EDGES);
    __syncthreads();

    // scatter records to final list slots (scn doubles as cursor)
    for (int r = start + tid; r < end; r += 256) {
        int v = rec[r];
        int dl = v >> shift;
        int pos = atomicAdd(&scn[dl], 1);
        list[start + pos] = v & mask;
    }
}

// ---- Fused per-hop gather + segment-sum + L2-norm + out accumulate ----
__global__ void gather_norm_v(const u16* __restrict__ srcU,
                              const u16* __restrict__ srcI,
                              const int* __restrict__ offs_u, const int* __restrict__ list_u,
                              const int* __restrict__ offs_i, const int* __restrict__ list_i,
                              u16* __restrict__ aggU, u16* __restrict__ aggI,
                              float* __restrict__ outU, float* __restrict__ outI,
                              const float* __restrict__ initU, const float* __restrict__ initI,
                              int first) {
    int t = blockIdx.x * blockDim.x + threadIdx.x;
    int r = t >> 6;
    int d = t & 63;
    const u16* src; const int* offs; const int* list;
    u16* agg; float* out; const float* init; int rr;
    if (r < N_USERS) {
        src = srcU; offs = offs_u; list = list_u;
        agg = aggU; out = outU; init = initU; rr = r;
    } else {
        src = srcI; offs = offs_i; list = list_i;
        agg = aggI; out = outI; init = initI; rr = r - N_USERS;
    }
    int beg = offs[rr];
    int end = offs[rr + 1];
    int g = end - beg;
    int gc = (g < 64) ? g : 64;
    int grp = d >> 3, sub = d & 7;

    int jl = (d < gc) ? list[beg + d] : 0;

    float acc[8] = {0.f, 0.f, 0.f, 0.f, 0.f, 0.f, 0.f, 0.f};

    int k = 0;
    for (; k + 8 <= gc; k += 8) {
        int j = __shfl(jl, k + grp);
        us8 v = *(const us8*)(src + (size_t)j * EMB + sub * 8);
        #pragma unroll
        for (int i = 0; i < 8; ++i) acc[i] += bf2f(v[i]);
    }
    int m = gc - k;
    if (m > 0) {
        int sl = k + ((grp < m) ? grp : 0);
        int j = __shfl(jl, sl);
        if (grp < m) {
            us8 v = *(const us8*)(src + (size_t)j * EMB + sub * 8);
            #pragma unroll
            for (int i = 0; i < 8; ++i) acc[i] += bf2f(v[i]);
        }
    }
    for (int kk = beg + 64 + grp; kk < end; kk += 8) {
        int j = list[kk];
        us8 v = *(const us8*)(src + (size_t)j * EMB + sub * 8);
        #pragma unroll
        for (int i = 0; i < 8; ++i) acc[i] += bf2f(v[i]);
    }

    #pragma unroll
    for (int o = 8; o < 64; o <<= 1) {
        #pragma unroll
        for (int i = 0; i < 8; ++i) acc[i] += __shfl_xor(acc[i], o);
    }

    float q = 0.f;
    #pragma unroll
    for (int i = 0; i < 8; ++i) q += acc[i] * acc[i];
    q += __shfl_xor(q, 1);
    q += __shfl_xor(q, 2);
    q += __shfl_xor(q, 4);

    float inv = 1.f / fmaxf(sqrtf(q), 1e-12f);
    float y[8];
    #pragma unroll
    for (int i = 0; i < 8; ++i) y[i] = acc[i] * inv;

    if (grp == 0) {
        size_t ro = (size_t)rr * EMB + sub * 8;
        us8 w;
        #pragma unroll
        for (int i = 0; i < 8; ++i) w[i] = f2bf(y[i]);
        *(us8*)(agg + ro) = w;

        f4 a0 = {y[0], y[1], y[2], y[3]};
        f4 a1 = {y[4], y[5], y[6], y[7]};
        f4 b0, b1;
        if (first) {
            b0 = *(const f4*)(init + ro);
            b1 = *(const f4*)(init + ro + 4);
        } else {
            b0 = *(const f4*)(out + ro);
            b1 = *(const f4*)(out + ro + 4);
        }
        *(f4*)(out + ro)     = a0 + b0;
        *(f4*)(out + ro + 4) = a1 + b1;
    }
}

extern "C" void kernel_launch(void* const* d_in, const int* in_sizes, int n_in,
                              void* d_out, int out_size, void* d_ws, size_t ws_size,
                              hipStream_t stream) {
    const float* user_emb = (const float*)d_in[0];
    const float* item_emb = (const float*)d_in[1];
    const int*   uidx     = (const int*)d_in[2];
    const int*   iidx     = (const int*)d_in[3];

    float* out      = (float*)d_out;
    float* out_item = out;                           // [N_ITEMS, 64]
    float* out_user = out + (size_t)N_ITEMS * EMB;   // [N_USERS, 64]

    // workspace layout: bf16 tables first (16B-aligned), then int arrays
    u16* ws16    = (u16*)d_ws;
    u16* ua_bf   = ws16;
    u16* ub_bf   = ua_bf + (size_t)N_USERS * EMB;
    u16* ia_bf   = ub_bf + (size_t)N_USERS * EMB;
    u16* ib_bf   = ia_bf + (size_t)N_ITEMS * EMB;
    u16* uemb_bf = ib_bf + (size_t)N_ITEMS * EMB;
    u16* iemb_bf = uemb_bf + (size_t)N_USERS * EMB;
    int* rec     = (int*)(iemb_bf + (size_t)N_ITEMS * EMB);
    int* list    = rec + 2 * N_EDGES;
    int* list_u  = list;
    int* list_i  = list + N_EDGES;
    int* offs_u  = list + 2 * N_EDGES;
    int* offs_i  = offs_u + (N_USERS + 1);
    int* H       = offs_i + (N_ITEMS + 1);
    int* HB      = H + HN;
    int* part    = HB + HN;

    // bf16 copies of the embeddings (hop-0 gather sources)
    conv_kernel<<<(N_USERS * EMB / 4 + 255) / 256, 256, 0, stream>>>(user_emb, uemb_bf, N_USERS * EMB / 4);
    conv_kernel<<<(N_ITEMS * EMB / 4 + 255) / 256, 256, 0, stream>>>(item_emb, iemb_bf, N_ITEMS * EMB / 4);

    // bucketed CSR build
    histA_kernel<<<B1, 256, 0, stream>>>(uidx, iidx, H);
    hscan_tile_kernel<<<HTILES, 256, 0, stream>>>(H, part);
    hscan_write_kernel<<<HTILES, 256, 0, stream>>>(H, part, HB);
    scatterA_kernel<<<B1, 256, 0, stream>>>(uidx, iidx, HB, rec);
    bucketB_kernel<<<2 * NBUK, 256, 0, stream>>>(HB, rec, offs_u, offs_i, list);

    // 3 hops
    const u16* us_bf = uemb_bf;
    const u16* is_bf = iemb_bf;
    const int nblocks = ((N_USERS + N_ITEMS) * EMB) / 256;  // 37500

    for (int hop = 0; hop < 3; ++hop) {
        u16* ud = (hop & 1) ? ub_bf : ua_bf;
        u16* id = (hop & 1) ? ib_bf : ia_bf;

        gather_norm_v<<<nblocks, 256, 0, stream>>>(
            is_bf, us_bf, offs_u, list_u, offs_i, list_i,
            ud, id, out_user, out_item, user_emb, item_emb, hop == 0);

        us_bf = ud;
        is_bf = id;
    }
}